// Round 1
// baseline (116.909 us; speedup 1.0000x reference)
//
#include <hip/hip_runtime.h>

#define EPS 1e-4f

constexpr int B  = 8;
constexpr int C  = 128;
constexpr int Tt = 9;
constexpr int T  = 8;
constexpr int H  = 64;
constexpr int W  = 64;
constexpr int HW = H * W;          // 4096
constexpr int HM = 256;
constexpr int WM = 256;
constexpr int HWM = HM * WM;       // 65536

// ws layout (float offsets)
constexpr int WS_TV     = 0;                    // B*HW        = 32768
constexpr int WS_RV     = WS_TV + B * HW;       // B*T*HW      = 262144
constexpr int WS_CM     = WS_RV + B * T * HW;   // B*T*HW
constexpr int WS_GS_ACC = WS_CM + B * T * HW;   // B*T = 64
constexpr int WS_GS_FIN = WS_GS_ACC + B * T;    // B*T = 64
// total = 557184 floats = 2.23 MB

// --- antialiased bilinear downsample 256 -> 64 (scale 1/4), one output pixel.
// jax.image.resize(..., 'bilinear', antialias=True): sample_f = 4*o + 1.5,
// taps j = 4o-2 .. 4o+5, unnormalized weights {1,3,5,7,7,5,3,1}, per-dim
// renormalized over in-range taps (interior sum 32, edges sum 28).
__device__ __forceinline__ float resample_px(const float* __restrict__ src,
                                             int y, int x) {
  const float wt[8] = {1.f, 3.f, 5.f, 7.f, 7.f, 5.f, 3.f, 1.f};
  int by = 4 * y - 2, bx = 4 * x - 2;
  float wx[8];
  float nx = 0.f;
  #pragma unroll
  for (int d = 0; d < 8; ++d) {
    int xx = bx + d;
    float w = (xx >= 0 && xx < WM) ? wt[d] : 0.f;
    wx[d] = w;
    nx += w;
  }
  float ny = 0.f;
  float sum = 0.f;
  #pragma unroll
  for (int dy = 0; dy < 8; ++dy) {
    int yy = by + dy;
    if (yy < 0 || yy >= HM) continue;
    ny += wt[dy];
    const float* row = src + yy * WM;
    float rowsum = 0.f;
    #pragma unroll
    for (int dx = 0; dx < 8; ++dx) {
      int xx = bx + dx;
      xx = xx < 0 ? 0 : (xx >= WM ? WM - 1 : xx);  // clamp addr; weight is 0 when OOB
      rowsum += wx[dx] * row[xx];
    }
    sum += wt[dy] * rowsum;
  }
  return sum / (ny * nx);
}

// Kernel A: compute tv (B maps) and rv (B*T maps) binary masks; zero gs accs.
__global__ __launch_bounds__(256) void mask_kernel(
    const float* __restrict__ tvmap, const float* __restrict__ rvmaps,
    float* __restrict__ ws) {
  int bid = blockIdx.x, tid = threadIdx.x;
  if (bid == 0 && tid < 2 * B * T) ws[WS_GS_ACC + tid] = 0.f;

  const float* src;
  float* dst;
  if (bid < B) {
    src = tvmap + (size_t)bid * HWM;
    dst = ws + WS_TV + bid * HW;
  } else {
    int i = bid - B;                 // i = b*T + t
    src = rvmaps + (size_t)i * HWM;
    dst = ws + WS_RV + i * HW;
  }
  for (int i = 0; i < HW / 256; ++i) {
    int p = i * 256 + tid;
    int y = p >> 6, x = p & 63;
    float v = resample_px(src, y, x);
    dst[p] = (v > 0.5f) ? 1.f : 0.f;
  }
}

// Kernel B: accumulate gs[b,t] = sum_{c,hw} tf * rf * (tv*rv)
// grid = B * 4 c-chunks * 16 hw-chunks = 512 blocks, 256 threads (1 px each)
__global__ __launch_bounds__(256) void gs_kernel(
    const float* __restrict__ values, float* __restrict__ ws) {
  int bid = blockIdx.x;
  int hwc = bid & 15, cc = (bid >> 4) & 3, b = bid >> 6;
  int tid = threadIdx.x;
  int hw = hwc * 256 + tid;

  float tvm = ws[WS_TV + b * HW + hw];
  float vm[T];
  #pragma unroll
  for (int t = 0; t < T; ++t) vm[t] = tvm * ws[WS_RV + (b * T + t) * HW + hw];

  float acc[T];
  #pragma unroll
  for (int t = 0; t < T; ++t) acc[t] = 0.f;

  const float* vb = values + (size_t)b * C * Tt * HW;
  for (int c = cc * 32; c < cc * 32 + 32; ++c) {
    const float* vc = vb + (size_t)c * Tt * HW;
    float tf = vc[hw];
    #pragma unroll
    for (int t = 0; t < T; ++t)
      acc[t] += tf * vc[(t + 1) * HW + hw] * vm[t];
  }

  __shared__ float red[4][T];
  int lane = tid & 63, wave = tid >> 6;
  #pragma unroll
  for (int t = 0; t < T; ++t) {
    float v = acc[t];
    #pragma unroll
    for (int m = 32; m > 0; m >>= 1) v += __shfl_xor(v, m);
    if (lane == 0) red[wave][t] = v;
  }
  __syncthreads();
  if (tid < T) {
    float s = red[0][tid] + red[1][tid] + red[2][tid] + red[3][tid];
    atomicAdd(&ws[WS_GS_ACC + b * T + tid], s);
  }
}

// Kernel C1: v_sum[b,t] + finalize gs. grid = 64 blocks (one per (b,t)).
__global__ __launch_bounds__(256) void gs_finalize_kernel(float* __restrict__ ws) {
  int bid = blockIdx.x;     // b*T + t
  int b = bid >> 3;
  int tid = threadIdx.x;
  float s = 0.f;
  for (int i = 0; i < HW / 256; ++i) {
    int hw = i * 256 + tid;
    s += ws[WS_TV + b * HW + hw] * ws[WS_RV + bid * HW + hw];
  }
  #pragma unroll
  for (int m = 32; m > 0; m >>= 1) s += __shfl_xor(s, m);
  __shared__ float red[4];
  int lane = tid & 63, wave = tid >> 6;
  if (lane == 0) red[wave] = s;
  __syncthreads();
  if (tid == 0) {
    float vs = red[0] + red[1] + red[2] + red[3];
    bool zero = vs < EPS;
    float g = zero ? 0.f : ws[WS_GS_ACC + bid];
    vs += zero ? 1.f : 0.f;
    ws[WS_GS_FIN + bid] = g / vs / (float)C;
  }
}

// Kernel C2: per-pixel softmax over T -> c_match in ws; write c_mask to both
// output locations. grid = B*16 = 128 blocks.
__global__ __launch_bounds__(256) void cmatch_kernel(float* __restrict__ ws,
                                                     float* __restrict__ out) {
  int bid = blockIdx.x;
  int b = bid >> 4, hwc = bid & 15;
  int hw = hwc * 256 + threadIdx.x;

  float mv[T], rvm[T];
  #pragma unroll
  for (int t = 0; t < T; ++t) {
    float g = ws[WS_GS_FIN + b * T + t];
    rvm[t] = ws[WS_RV + (b * T + t) * HW + hw];
    mv[t] = g * rvm[t];
  }
  float mx = mv[0];
  #pragma unroll
  for (int t = 1; t < T; ++t) mx = fmaxf(mx, mv[t]);
  float me[T];
  float s = 0.f;
  #pragma unroll
  for (int t = 0; t < T; ++t) {
    me[t] = expf(mv[t] - mx) * rvm[t];
    s += me[t];
  }
  s += (s < EPS) ? 1.f : 0.f;
  float inv = 1.f / s;
  float csum = 0.f;
  #pragma unroll
  for (int t = 0; t < T; ++t) {
    float cmv = me[t] * inv;
    ws[WS_CM + (b * T + t) * HW + hw] = cmv;
    csum += cmv;
  }
  float cmask = 1.f - csum;
  out[((size_t)b * 257 + 256) * HW + hw] = cmask;           // out channel 256
  out[(size_t)B * 257 * HW + (size_t)b * HW + hw] = cmask;  // second output
}

// Kernel D: t_feat copy + c_out = sum_t r_feats * c_match.
// grid = B * 4 c-chunks * 16 hw-chunks = 512 blocks.
__global__ __launch_bounds__(256) void out_kernel(
    const float* __restrict__ values, const float* __restrict__ ws,
    float* __restrict__ out) {
  int bid = blockIdx.x;
  int hwc = bid & 15, cc = (bid >> 4) & 3, b = bid >> 6;
  int hw = hwc * 256 + threadIdx.x;

  float cm[T];
  #pragma unroll
  for (int t = 0; t < T; ++t) cm[t] = ws[WS_CM + (b * T + t) * HW + hw];

  const float* vb = values + (size_t)b * C * Tt * HW;
  for (int c = cc * 32; c < cc * 32 + 32; ++c) {
    const float* vc = vb + (size_t)c * Tt * HW;
    float tf = vc[hw];
    float acc = 0.f;
    #pragma unroll
    for (int t = 0; t < T; ++t) acc += vc[(t + 1) * HW + hw] * cm[t];
    out[((size_t)b * 257 + c) * HW + hw] = tf;
    out[((size_t)b * 257 + 128 + c) * HW + hw] = acc;
  }
}

extern "C" void kernel_launch(void* const* d_in, const int* in_sizes, int n_in,
                              void* d_out, int out_size, void* d_ws, size_t ws_size,
                              hipStream_t stream) {
  const float* values = (const float*)d_in[0];
  const float* tvmap  = (const float*)d_in[1];
  const float* rvmaps = (const float*)d_in[2];
  float* out = (float*)d_out;
  float* ws  = (float*)d_ws;

  hipLaunchKernelGGL(mask_kernel, dim3(B * (T + 1)), dim3(256), 0, stream,
                     tvmap, rvmaps, ws);
  hipLaunchKernelGGL(gs_kernel, dim3(B * 4 * 16), dim3(256), 0, stream,
                     values, ws);
  hipLaunchKernelGGL(gs_finalize_kernel, dim3(B * T), dim3(256), 0, stream, ws);
  hipLaunchKernelGGL(cmatch_kernel, dim3(B * 16), dim3(256), 0, stream, ws, out);
  hipLaunchKernelGGL(out_kernel, dim3(B * 4 * 16), dim3(256), 0, stream,
                     values, ws, out);
}

// Round 2
// 77.174 us; speedup vs baseline: 1.5149x; 1.5149x over previous
//
#include <hip/hip_runtime.h>

#define EPS 1e-4f

constexpr int B  = 8;
constexpr int C  = 128;
constexpr int Tt = 9;
constexpr int T  = 8;
constexpr int H  = 64;
constexpr int W  = 64;
constexpr int HW = H * W;          // 4096
constexpr int HM = 256;
constexpr int WM = 256;
constexpr int HWM = HM * WM;       // 65536

typedef __attribute__((ext_vector_type(4))) float f32x4;

// ws layout (float offsets)
constexpr int WS_TV     = 0;                    // B*HW        = 32768
constexpr int WS_RV     = WS_TV + B * HW;       // B*T*HW      = 262144
constexpr int WS_GS_ACC = WS_RV + B * T * HW;   // 64
constexpr int WS_VS_ACC = WS_GS_ACC + B * T;    // 64
constexpr int WS_GS_FIN = WS_VS_ACC + B * T;    // 64

__device__ __forceinline__ const f32x4& ld4(const float* p) {
  return *reinterpret_cast<const f32x4*>(p);
}
__device__ __forceinline__ void st4(float* p, f32x4 v) {
  *reinterpret_cast<f32x4*>(p) = v;
}

// --- antialiased bilinear downsample 256 -> 64 (scale 1/4), one output pixel.
// jax.image.resize 'bilinear' antialias=True: sample = 4o+1.5, taps 4o-2..4o+5,
// unnormalized weights {1,3,5,7,7,5,3,1}, per-dim renormalized over valid taps.
__device__ __forceinline__ float resample_px(const float* __restrict__ src,
                                             int y, int x) {
  const float wt[8] = {1.f, 3.f, 5.f, 7.f, 7.f, 5.f, 3.f, 1.f};
  int by = 4 * y - 2, bx = 4 * x - 2;
  float wx[8];
  float nx = 0.f;
  #pragma unroll
  for (int d = 0; d < 8; ++d) {
    int xx = bx + d;
    float w = (xx >= 0 && xx < WM) ? wt[d] : 0.f;
    wx[d] = w;
    nx += w;
  }
  float ny = 0.f;
  float sum = 0.f;
  #pragma unroll
  for (int dy = 0; dy < 8; ++dy) {
    int yy = by + dy;
    if (yy < 0 || yy >= HM) continue;
    ny += wt[dy];
    const float* row = src + yy * WM;
    float rowsum = 0.f;
    #pragma unroll
    for (int dx = 0; dx < 8; ++dx) {
      int xx = bx + dx;
      xx = xx < 0 ? 0 : (xx >= WM ? WM - 1 : xx);  // clamp addr; weight 0 if OOB
      rowsum += wx[dx] * row[xx];
    }
    sum += wt[dy] * rowsum;
  }
  return sum / (ny * nx);
}

// Kernel A: masks (grid-strided over all 72 maps * 4096 px) + zero accums.
__global__ __launch_bounds__(256) void mask_kernel(
    const float* __restrict__ tvmap, const float* __restrict__ rvmaps,
    float* __restrict__ ws) {
  int gtid = blockIdx.x * 256 + threadIdx.x;
  if (gtid < 2 * B * T) ws[WS_GS_ACC + gtid] = 0.f;  // gs_acc + vs_acc

  constexpr int TOTAL = (B + B * T) * HW;  // 294912
  for (int p = gtid; p < TOTAL; p += 512 * 256) {
    int m = p >> 12;          // map index 0..71
    int px = p & (HW - 1);
    int y = px >> 6, x = px & 63;
    const float* src;
    float* dst;
    if (m < B) {
      src = tvmap + (size_t)m * HWM;
      dst = ws + WS_TV + m * HW;
    } else {
      src = rvmaps + (size_t)(m - B) * HWM;
      dst = ws + WS_RV + (m - B) * HW;
    }
    float v = resample_px(src, y, x);
    dst[px] = (v > 0.5f) ? 1.f : 0.f;
  }
}

// Kernel B: gs[b,t] += sum_{c,px} tf*rf*vm ; v_sum[b,t] += sum_px vm (cc==0);
// t_feat copy to out channels 0..127.  grid = b(8) x cc(16) x hq(4) = 512.
__global__ __launch_bounds__(256) void gs_kernel(
    const float* __restrict__ values, float* __restrict__ ws,
    float* __restrict__ out) {
  int bid = blockIdx.x;
  int hq = bid & 3, cc = (bid >> 2) & 15, b = bid >> 6;
  int tid = threadIdx.x;
  int px = hq * 1024 + tid * 4;

  f32x4 tv = ld4(ws + WS_TV + b * HW + px);
  f32x4 vm[T];
  #pragma unroll
  for (int t = 0; t < T; ++t)
    vm[t] = tv * ld4(ws + WS_RV + (b * T + t) * HW + px);

  float acc[T];
  #pragma unroll
  for (int t = 0; t < T; ++t) acc[t] = 0.f;

  const float* vb = values + (size_t)(b * C + cc * 8) * Tt * HW;
  #pragma unroll
  for (int c = 0; c < 8; ++c) {
    const float* vc = vb + (size_t)c * Tt * HW;
    f32x4 tf = ld4(vc + px);
    st4(out + ((size_t)b * 257 + cc * 8 + c) * HW + px, tf);  // t_feat copy
    #pragma unroll
    for (int t = 0; t < T; ++t) {
      f32x4 rf = ld4(vc + (t + 1) * HW + px);
      #pragma unroll
      for (int j = 0; j < 4; ++j) acc[t] += tf[j] * rf[j] * vm[t][j];
    }
  }

  __shared__ float red[4][T];
  int lane = tid & 63, wave = tid >> 6;
  #pragma unroll
  for (int t = 0; t < T; ++t) {
    float v = acc[t];
    #pragma unroll
    for (int m = 32; m > 0; m >>= 1) v += __shfl_xor(v, m);
    if (lane == 0) red[wave][t] = v;
  }
  __syncthreads();
  if (tid < T) {
    float s = red[0][tid] + red[1][tid] + red[2][tid] + red[3][tid];
    atomicAdd(&ws[WS_GS_ACC + b * T + tid], s);
  }

  if (cc == 0) {
    __syncthreads();
    float vs[T];
    #pragma unroll
    for (int t = 0; t < T; ++t)
      vs[t] = vm[t][0] + vm[t][1] + vm[t][2] + vm[t][3];
    #pragma unroll
    for (int t = 0; t < T; ++t) {
      float v = vs[t];
      #pragma unroll
      for (int m = 32; m > 0; m >>= 1) v += __shfl_xor(v, m);
      if (lane == 0) red[wave][t] = v;
    }
    __syncthreads();
    if (tid < T) {
      float s = red[0][tid] + red[1][tid] + red[2][tid] + red[3][tid];
      atomicAdd(&ws[WS_VS_ACC + b * T + tid], s);
    }
  }
}

// Kernel C: finalize gs. 1 block, 64 threads.
__global__ __launch_bounds__(64) void gs_finalize_kernel(float* __restrict__ ws) {
  int tid = threadIdx.x;
  float vs = ws[WS_VS_ACC + tid];   // exact integer count
  float g  = ws[WS_GS_ACC + tid];
  bool zero = vs < EPS;
  float gv = zero ? 0.f : g;
  vs += zero ? 1.f : 0.f;
  ws[WS_GS_FIN + tid] = gv / vs / (float)C;
}

// Kernel D: per-px softmax over T + c_out + c_mask. grid = 512 like B.
__global__ __launch_bounds__(256) void out_kernel(
    const float* __restrict__ values, const float* __restrict__ ws,
    float* __restrict__ out) {
  int bid = blockIdx.x;
  int hq = bid & 3, cc = (bid >> 2) & 15, b = bid >> 6;
  int tid = threadIdx.x;
  int px = hq * 1024 + tid * 4;

  float gsf[T];
  #pragma unroll
  for (int t = 0; t < T; ++t) gsf[t] = ws[WS_GS_FIN + b * T + t];

  f32x4 rv[T], cm[T];
  #pragma unroll
  for (int t = 0; t < T; ++t)
    rv[t] = ld4(ws + WS_RV + (b * T + t) * HW + px);

  // masked_vec = gsf*rv (zeros where rv=0 participate in the max)
  f32x4 mx = gsf[0] * rv[0];
  #pragma unroll
  for (int t = 1; t < T; ++t) {
    f32x4 v = gsf[t] * rv[t];
    #pragma unroll
    for (int j = 0; j < 4; ++j) mx[j] = fmaxf(mx[j], v[j]);
  }
  f32x4 s = {0.f, 0.f, 0.f, 0.f};
  #pragma unroll
  for (int t = 0; t < T; ++t) {
    #pragma unroll
    for (int j = 0; j < 4; ++j)
      cm[t][j] = expf(gsf[t] * rv[t][j] - mx[j]) * rv[t][j];
    s += cm[t];
  }
  #pragma unroll
  for (int j = 0; j < 4; ++j) {
    s[j] += (s[j] < EPS) ? 1.f : 0.f;
    s[j] = 1.f / s[j];
  }
  f32x4 csum = {0.f, 0.f, 0.f, 0.f};
  #pragma unroll
  for (int t = 0; t < T; ++t) {
    cm[t] *= s;
    csum += cm[t];
  }

  if (cc == 0) {
    f32x4 cmask;
    #pragma unroll
    for (int j = 0; j < 4; ++j) cmask[j] = 1.f - csum[j];
    st4(out + ((size_t)b * 257 + 256) * HW + px, cmask);
    st4(out + (size_t)B * 257 * HW + (size_t)b * HW + px, cmask);
  }

  const float* vb = values + (size_t)(b * C + cc * 8) * Tt * HW;
  #pragma unroll
  for (int c = 0; c < 8; ++c) {
    const float* vc = vb + (size_t)c * Tt * HW;
    f32x4 acc = {0.f, 0.f, 0.f, 0.f};
    #pragma unroll
    for (int t = 0; t < T; ++t) {
      f32x4 rf = ld4(vc + (t + 1) * HW + px);
      acc += rf * cm[t];
    }
    st4(out + ((size_t)b * 257 + 128 + cc * 8 + c) * HW + px, acc);
  }
}

extern "C" void kernel_launch(void* const* d_in, const int* in_sizes, int n_in,
                              void* d_out, int out_size, void* d_ws, size_t ws_size,
                              hipStream_t stream) {
  const float* values = (const float*)d_in[0];
  const float* tvmap  = (const float*)d_in[1];
  const float* rvmaps = (const float*)d_in[2];
  float* out = (float*)d_out;
  float* ws  = (float*)d_ws;

  hipLaunchKernelGGL(mask_kernel, dim3(512), dim3(256), 0, stream,
                     tvmap, rvmaps, ws);
  hipLaunchKernelGGL(gs_kernel, dim3(512), dim3(256), 0, stream,
                     values, ws, out);
  hipLaunchKernelGGL(gs_finalize_kernel, dim3(1), dim3(64), 0, stream, ws);
  hipLaunchKernelGGL(out_kernel, dim3(512), dim3(256), 0, stream,
                     values, ws, out);
}

// Round 3
// 76.156 us; speedup vs baseline: 1.5351x; 1.0134x over previous
//
#include <hip/hip_runtime.h>

#define EPS 1e-4f

constexpr int B  = 8;
constexpr int C  = 128;
constexpr int Tt = 9;
constexpr int T  = 8;
constexpr int H  = 64;
constexpr int W  = 64;
constexpr int HW = H * W;          // 4096
constexpr int HM = 256;
constexpr int WM = 256;
constexpr int HWM = HM * WM;       // 65536

typedef __attribute__((ext_vector_type(4))) float f32x4;

// ws layout (float offsets). Every cell is written before it is read, every
// replay — no cross-replay state, no zero-init needed.
constexpr int WS_TV  = 0;                      // B*HW      = 32768
constexpr int WS_RV  = WS_TV + B * HW;         // B*T*HW    = 262144
constexpr int WS_GSP = WS_RV + B * T * HW;     // per-block gs partials [b][cc*4+hq][t] = 4096
constexpr int WS_VSP = WS_GSP + B * 64 * T;    // vs partials [b][hq][t] = 256

__device__ __forceinline__ const f32x4& ld4(const float* p) {
  return *reinterpret_cast<const f32x4*>(p);
}
__device__ __forceinline__ void st4(float* p, f32x4 v) {
  *reinterpret_cast<f32x4*>(p) = v;
}

// --- antialiased bilinear downsample 256 -> 64 (scale 1/4), one output pixel.
// jax.image.resize 'bilinear' antialias=True: sample = 4o+1.5, taps 4o-2..4o+5,
// unnormalized weights {1,3,5,7,7,5,3,1}, per-dim renormalized over valid taps.
__device__ __forceinline__ float resample_px(const float* __restrict__ src,
                                             int y, int x) {
  const float wt[8] = {1.f, 3.f, 5.f, 7.f, 7.f, 5.f, 3.f, 1.f};
  int by = 4 * y - 2, bx = 4 * x - 2;
  float wx[8];
  float nx = 0.f;
  #pragma unroll
  for (int d = 0; d < 8; ++d) {
    int xx = bx + d;
    float w = (xx >= 0 && xx < WM) ? wt[d] : 0.f;
    wx[d] = w;
    nx += w;
  }
  float ny = 0.f;
  float sum = 0.f;
  #pragma unroll
  for (int dy = 0; dy < 8; ++dy) {
    int yy = by + dy;
    if (yy < 0 || yy >= HM) continue;
    ny += wt[dy];
    const float* row = src + yy * WM;
    float rowsum = 0.f;
    #pragma unroll
    for (int dx = 0; dx < 8; ++dx) {
      int xx = bx + dx;
      xx = xx < 0 ? 0 : (xx >= WM ? WM - 1 : xx);  // clamp addr; weight 0 if OOB
      rowsum += wx[dx] * row[xx];
    }
    sum += wt[dy] * rowsum;
  }
  return sum / (ny * nx);
}

// Kernel A: masks, grid-strided over all 72 maps * 4096 px.
__global__ __launch_bounds__(256) void mask_kernel(
    const float* __restrict__ tvmap, const float* __restrict__ rvmaps,
    float* __restrict__ ws) {
  int gtid = blockIdx.x * 256 + threadIdx.x;
  constexpr int TOTAL = (B + B * T) * HW;  // 294912
  for (int p = gtid; p < TOTAL; p += 512 * 256) {
    int m = p >> 12;          // map index 0..71
    int px = p & (HW - 1);
    int y = px >> 6, x = px & 63;
    const float* src;
    float* dst;
    if (m < B) {
      src = tvmap + (size_t)m * HWM;
      dst = ws + WS_TV + m * HW;
    } else {
      src = rvmaps + (size_t)(m - B) * HWM;
      dst = ws + WS_RV + (m - B) * HW;
    }
    float v = resample_px(src, y, x);
    dst[px] = (v > 0.5f) ? 1.f : 0.f;
  }
}

// Kernel B: pure streaming pass over values -> per-block gs partials (+ vs
// partials from cc==0 blocks). grid = b(8) x cc(16) x hq(4) = 512, 256 thr.
__global__ __launch_bounds__(256) void gs_kernel(
    const float* __restrict__ values, float* __restrict__ ws) {
  int bid = blockIdx.x;
  int hq = bid & 3, cc = (bid >> 2) & 15, b = bid >> 6;
  int tid = threadIdx.x;
  int px = hq * 1024 + tid * 4;

  f32x4 tv = ld4(ws + WS_TV + b * HW + px);
  f32x4 vm[T];
  #pragma unroll
  for (int t = 0; t < T; ++t)
    vm[t] = tv * ld4(ws + WS_RV + (b * T + t) * HW + px);

  float acc[T];
  #pragma unroll
  for (int t = 0; t < T; ++t) acc[t] = 0.f;

  const float* vb = values + (size_t)(b * C + cc * 8) * Tt * HW;
  #pragma unroll
  for (int c = 0; c < 8; ++c) {
    const float* vc = vb + (size_t)c * Tt * HW;
    f32x4 tf = ld4(vc + px);
    #pragma unroll
    for (int t = 0; t < T; ++t) {
      f32x4 rf = ld4(vc + (t + 1) * HW + px);
      #pragma unroll
      for (int j = 0; j < 4; ++j) acc[t] += tf[j] * rf[j] * vm[t][j];
    }
  }

  __shared__ float red[4][T];
  int lane = tid & 63, wave = tid >> 6;
  #pragma unroll
  for (int t = 0; t < T; ++t) {
    float v = acc[t];
    #pragma unroll
    for (int m = 32; m > 0; m >>= 1) v += __shfl_xor(v, m);
    if (lane == 0) red[wave][t] = v;
  }
  __syncthreads();
  if (tid < T) {
    float s = red[0][tid] + red[1][tid] + red[2][tid] + red[3][tid];
    ws[WS_GSP + ((b * 16 + cc) * 4 + hq) * T + tid] = s;
  }

  if (cc == 0) {
    __syncthreads();   // ensure tid<T finished reading red before overwrite
    #pragma unroll
    for (int t = 0; t < T; ++t) {
      float v = vm[t][0] + vm[t][1] + vm[t][2] + vm[t][3];
      #pragma unroll
      for (int m = 32; m > 0; m >>= 1) v += __shfl_xor(v, m);
      if (lane == 0) red[wave][t] = v;
    }
    __syncthreads();
    if (tid < T) {
      float s = red[0][tid] + red[1][tid] + red[2][tid] + red[3][tid];
      ws[WS_VSP + (b * 4 + hq) * T + tid] = s;
    }
  }
}

// Kernel C: finalize gs (redundant per block, tiny) + per-px softmax over T +
// t_feat copy + c_out + c_mask. grid = 512, 256 thr.
__global__ __launch_bounds__(256) void out_kernel(
    const float* __restrict__ values, const float* __restrict__ ws,
    float* __restrict__ out) {
  int bid = blockIdx.x;
  int hq = bid & 3, cc = (bid >> 2) & 15, b = bid >> 6;
  int tid = threadIdx.x;
  int px = hq * 1024 + tid * 4;

  // --- finalize gs[b,*] from partials (64 gs partials + 4 vs partials per t)
  __shared__ float gsf_sh[T];
  if (tid < 64) {
    int t = tid >> 3, part = tid & 7;
    float s = 0.f;
    #pragma unroll
    for (int k = 0; k < 8; ++k) {
      int f = part * 8 + k;           // flattened (cc*4+hq) in 0..63
      s += ws[WS_GSP + (b * 64 + f) * T + t];
    }
    #pragma unroll
    for (int m = 1; m < 8; m <<= 1) s += __shfl_xor(s, m);
    if (part == 0) {
      float vs = 0.f;
      #pragma unroll
      for (int h = 0; h < 4; ++h) vs += ws[WS_VSP + (b * 4 + h) * T + t];
      bool zero = vs < EPS;           // vs is an exact integer-valued count
      float g = zero ? 0.f : s;
      vs += zero ? 1.f : 0.f;
      gsf_sh[t] = g / vs / (float)C;
    }
  }
  __syncthreads();

  float gsf[T];
  #pragma unroll
  for (int t = 0; t < T; ++t) gsf[t] = gsf_sh[t];

  f32x4 rv[T], cm[T];
  #pragma unroll
  for (int t = 0; t < T; ++t)
    rv[t] = ld4(ws + WS_RV + (b * T + t) * HW + px);

  // masked_vec = gsf*rv (zeros where rv=0 participate in the max)
  f32x4 mx = gsf[0] * rv[0];
  #pragma unroll
  for (int t = 1; t < T; ++t) {
    f32x4 v = gsf[t] * rv[t];
    #pragma unroll
    for (int j = 0; j < 4; ++j) mx[j] = fmaxf(mx[j], v[j]);
  }
  f32x4 s = {0.f, 0.f, 0.f, 0.f};
  #pragma unroll
  for (int t = 0; t < T; ++t) {
    #pragma unroll
    for (int j = 0; j < 4; ++j)
      cm[t][j] = expf(gsf[t] * rv[t][j] - mx[j]) * rv[t][j];
    s += cm[t];
  }
  #pragma unroll
  for (int j = 0; j < 4; ++j) {
    s[j] += (s[j] < EPS) ? 1.f : 0.f;
    s[j] = 1.f / s[j];
  }
  f32x4 csum = {0.f, 0.f, 0.f, 0.f};
  #pragma unroll
  for (int t = 0; t < T; ++t) {
    cm[t] *= s;
    csum += cm[t];
  }

  if (cc == 0) {
    f32x4 cmask;
    #pragma unroll
    for (int j = 0; j < 4; ++j) cmask[j] = 1.f - csum[j];
    st4(out + ((size_t)b * 257 + 256) * HW + px, cmask);
    st4(out + (size_t)B * 257 * HW + (size_t)b * HW + px, cmask);
  }

  const float* vb = values + (size_t)(b * C + cc * 8) * Tt * HW;
  #pragma unroll
  for (int c = 0; c < 8; ++c) {
    const float* vc = vb + (size_t)c * Tt * HW;
    f32x4 tf = ld4(vc + px);
    st4(out + ((size_t)b * 257 + cc * 8 + c) * HW + px, tf);  // t_feat copy
    f32x4 acc = {0.f, 0.f, 0.f, 0.f};
    #pragma unroll
    for (int t = 0; t < T; ++t) {
      f32x4 rf = ld4(vc + (t + 1) * HW + px);
      acc += rf * cm[t];
    }
    st4(out + ((size_t)b * 257 + 128 + cc * 8 + c) * HW + px, acc);
  }
}

extern "C" void kernel_launch(void* const* d_in, const int* in_sizes, int n_in,
                              void* d_out, int out_size, void* d_ws, size_t ws_size,
                              hipStream_t stream) {
  const float* values = (const float*)d_in[0];
  const float* tvmap  = (const float*)d_in[1];
  const float* rvmaps = (const float*)d_in[2];
  float* out = (float*)d_out;
  float* ws  = (float*)d_ws;

  hipLaunchKernelGGL(mask_kernel, dim3(512), dim3(256), 0, stream,
                     tvmap, rvmaps, ws);
  hipLaunchKernelGGL(gs_kernel, dim3(512), dim3(256), 0, stream,
                     values, ws);
  hipLaunchKernelGGL(out_kernel, dim3(512), dim3(256), 0, stream,
                     values, ws, out);
}